// Round 8
// baseline (115.066 us; speedup 1.0000x reference)
//
#include <hip/hip_runtime.h>

// Problem constants (fixed by the reference)
#define BATCH   8192
#define GROUPS  512
#define ARITY   3
#define OUT_DIM 16
#define NV      27          // 3^3 vertices
#define XCOLS   (GROUPS*ARITY)      // 1536
#define OCOLS   (GROUPS*OUT_DIM)    // 8192

// MFMA structure: per group, out[b,o] = sum_v basis[b,v] * P[v,o] is a
// [16x27]x[27x16] GEMM per tile -> v_mfma_f32_16x16x32_bf16.
// k-slot map (same for A and B, so any HW k-permutation cancels):
//   slot (q = lane>>4, e = 0..7) -> vertex v = 9q + e, digits (e%3, e/3, q)
//   -> basis = (w0[e%3]*w1[e/3]) * w2[q]: static indices + one w2sel select.
// The 3 vertices with (d0,d1)=(2,2) (v = 8+9q) go in a 2nd MFMA (A2/B2,
// element 0 only). q==3 slots are zeroed via w2sel=0.
// B-frag (params, bf16, 4 VGPR) loaded ONCE per wave -> no per-iter param
// traffic (R6's DS-pipe cost, ~56us, eliminated).
// Block = 512 thr = 8 waves = 8 groups; BCHUNK=128 batch rows (8 tiles/wave).
#define GTILE   8
#define BCHUNK  128
#define NTILES  (BCHUNK/16)

typedef short bf16x8 __attribute__((ext_vector_type(8)));
typedef float f32x4  __attribute__((ext_vector_type(4)));

__device__ __forceinline__ unsigned cvt_pk_bf16(float lo, float hi) {
    unsigned r;
    asm("v_cvt_pk_bf16_f32 %0, %1, %2" : "=v"(r) : "v"(lo), "v"(hi));
    return r;
}

__global__ __launch_bounds__(512, 8) void lattice_mfma_kernel(
    const float* __restrict__ X,
    const float* __restrict__ P,
    float* __restrict__ out)
{
    __shared__ float xs[BCHUNK * GTILE * ARITY];   // 128*24 floats = 12 KiB

    const int t  = threadIdx.x;
    const int b0 = blockIdx.x * BCHUNK;
    const int g0 = blockIdx.y * GTILE;

    // ---- stage X rows [b0,b0+128) cols [g0*3,+24): 768 float4, linear LDS.
    {
        const float* src_base = X + (size_t)b0 * XCOLS + g0 * ARITY;
        #pragma unroll
        for (int k = 0; k < 2; ++k) {
            const int f = t + k * 512;
            if (f < (BCHUNK * GTILE * ARITY) / 4) {
                const int r = f / 6, c = f % 6;
                const float* src = src_base + (size_t)r * XCOLS + c * 4;
                __builtin_amdgcn_global_load_lds(
                    (const __attribute__((address_space(1))) void*)src,
                    (__attribute__((address_space(3))) void*)&xs[f * 4],
                    16, 0, 0);
            }
        }
    }

    const int wv = t >> 6;        // wave index = group-local 0..7
    const int l  = t & 63;
    const int n  = l & 15;        // B/C col (o) and A row (b-row within tile)
    const int q  = l >> 4;        // k-quad
    const int qc = (q > 2) ? 2 : q;   // q==3 slots are zeroed on the A side
    const int g  = g0 + wv;

    // ---- B fragments (params as bf16), loaded once, live in 8 VGPRs.
    bf16x8 B1, B2;
    {
        const float* Pg = P + (size_t)g * (NV * OUT_DIM) + n;
        float pv[8];
        #pragma unroll
        for (int e = 0; e < 8; ++e) pv[e] = Pg[(9 * qc + e) * OUT_DIM];
        union { unsigned u[4]; bf16x8 v; } ub;
        #pragma unroll
        for (int e = 0; e < 4; ++e) ub.u[e] = cvt_pk_bf16(pv[2*e], pv[2*e+1]);
        B1 = ub.v;
        union { unsigned u[4]; bf16x8 v; } ub2;
        ub2.u[0] = cvt_pk_bf16(Pg[(8 + 9 * qc) * OUT_DIM], 0.0f);
        ub2.u[1] = 0; ub2.u[2] = 0; ub2.u[3] = 0;
        B2 = ub2.v;
    }

    __syncthreads();   // drains global_load_lds

    // C layout (HW-verified): col = lane&15 (=n), row = q*4 + reg.
    float* outb = out + (size_t)(b0 + 4 * q) * OCOLS + (size_t)g * OUT_DIM + n;
    const float* xw = xs + wv * ARITY;

    #pragma unroll 1
    for (int tt = 0; tt < NTILES; ++tt) {
        const int row = tt * 16 + n;             // A row m = lane&15
        const float x0 = xw[row * (GTILE * ARITY) + 0];
        const float x1 = xw[row * (GTILE * ARITY) + 1];
        const float x2 = xw[row * (GTILE * ARITY) + 2];

        // hat basis over {-1,0,+1}
        const float w00 = fmaxf(-x0, 0.f), w01 = 1.f - fabsf(x0), w02 = fmaxf(x0, 0.f);
        const float w10 = fmaxf(-x1, 0.f), w11 = 1.f - fabsf(x1), w12 = fmaxf(x1, 0.f);
        const float w20 = fmaxf(-x2, 0.f), w21 = 1.f - fabsf(x2), w22 = fmaxf(x2, 0.f);

        const float w2sel = (q == 0) ? w20 : (q == 1) ? w21 : (q == 2) ? w22 : 0.0f;

        // slot e -> (d0,d1) = (e%3, e/3), all static
        const float a0 = w00 * w10 * w2sel;
        const float a1 = w01 * w10 * w2sel;
        const float a2 = w02 * w10 * w2sel;
        const float a3 = w00 * w11 * w2sel;
        const float a4 = w01 * w11 * w2sel;
        const float a5 = w02 * w11 * w2sel;
        const float a6 = w00 * w12 * w2sel;
        const float a7 = w01 * w12 * w2sel;
        const float a8 = w02 * w12 * w2sel;   // (d0,d1)=(2,2) vertex, v=8+9q

        union { unsigned u[4]; bf16x8 v; } ua;
        ua.u[0] = cvt_pk_bf16(a0, a1);
        ua.u[1] = cvt_pk_bf16(a2, a3);
        ua.u[2] = cvt_pk_bf16(a4, a5);
        ua.u[3] = cvt_pk_bf16(a6, a7);
        union { unsigned u[4]; bf16x8 v; } ua2;
        ua2.u[0] = cvt_pk_bf16(a8, 0.0f);
        ua2.u[1] = 0; ua2.u[2] = 0; ua2.u[3] = 0;

        f32x4 acc = {0.f, 0.f, 0.f, 0.f};
        acc = __builtin_amdgcn_mfma_f32_16x16x32_bf16(ua.v,  B1, acc, 0, 0, 0);
        acc = __builtin_amdgcn_mfma_f32_16x16x32_bf16(ua2.v, B2, acc, 0, 0, 0);

        // 4 nt stores; each wave-instr = 4 x 64B aligned segments (HBM granule)
        #pragma unroll
        for (int r = 0; r < 4; ++r)
            __builtin_nontemporal_store(acc[r], outb + (size_t)(tt * 16 + r) * OCOLS);
    }
}

extern "C" void kernel_launch(void* const* d_in, const int* in_sizes, int n_in,
                              void* d_out, int out_size, void* d_ws, size_t ws_size,
                              hipStream_t stream) {
    const float* X = (const float*)d_in[0];   // [8192, 1536] f32
    const float* P = (const float*)d_in[1];   // [512, 27, 16] f32
    float* out = (float*)d_out;               // [8192, 8192] f32

    dim3 grid(BATCH / BCHUNK, GROUPS / GTILE); // 64 x 64 = 4096 blocks
    dim3 block(512);
    lattice_mfma_kernel<<<grid, block, 0, stream>>>(X, P, out);
}

// Round 9
// 72.737 us; speedup vs baseline: 1.5819x; 1.5819x over previous
//
#include <hip/hip_runtime.h>

// Problem constants (fixed by the reference)
#define BATCH   8192
#define GROUPS  512
#define ARITY   3
#define OUT_DIM 16
#define NV      27          // 3^3 vertices
#define XCOLS   (GROUPS*ARITY)      // 1536
#define OCOLS   (GROUPS*OUT_DIM)    // 8192

// R9: R6's 8-corner LDS-gather structure, but params in LDS as bf16 and
// lane widened to 4 outputs -> each vertex gather is one ds_read_b64
// covering 4 outputs (vs 2 in R6): DS instrs per output byte halved
// (DS-busy ~56us -> ~28us, under the ~55us HBM stream).
// Block = 256 thr = 4 waves; lane = (gl = l>>2 in 0..15, oq = l&3).
// Wave owns 8 batches; block = 32 b x 16 g.
// LDS: X 32x48 f32 = 6144B + params 16 x 444 bf16 = 14208B -> 20352B
// -> exactly 8 blocks/CU = 32 waves/CU (max).
// PSTRIDE=444: group base words gl*222 %32 = -2gl -> 16 distinct banks.
// nt stores kept (A/B proven +10us, R6 vs R7); b128 nt = 1KB/wave-instr.
#define BTILE 32
#define GTILE 16
#define PSTRIDE 444     // bf16 elems per group (432 + 12 pad)

typedef float    f32x4 __attribute__((ext_vector_type(4)));
typedef unsigned u32x2 __attribute__((ext_vector_type(2)));

__device__ __forceinline__ unsigned cvt_pk_bf16(float lo, float hi) {
    unsigned r;
    asm("v_cvt_pk_bf16_f32 %0, %1, %2" : "=v"(r) : "v"(lo), "v"(hi));
    return r;
}
__device__ __forceinline__ float bflo(unsigned u) {
    union { unsigned u; float f; } c; c.u = u << 16; return c.f;
}
__device__ __forceinline__ float bfhi(unsigned u) {
    union { unsigned u; float f; } c; c.u = u & 0xffff0000u; return c.f;
}

__global__ __launch_bounds__(256, 8) void lattice_interp_kernel(
    const float* __restrict__ X,
    const float* __restrict__ P,
    float* __restrict__ out)
{
    __shared__ float xs[BTILE * GTILE * ARITY];        // 1536 f32 = 6144 B
    __shared__ unsigned short ps[GTILE * PSTRIDE];     // 7104 bf16 = 14208 B

    const int t  = threadIdx.x;
    const int b0 = blockIdx.x * BTILE;
    const int g0 = blockIdx.y * GTILE;

    // ---- stage X rows [b0,b0+32) cols [g0*3, g0*3+48): 384 float4, linear.
    {
        const float* src_base = X + (size_t)b0 * XCOLS + g0 * ARITY;
        #pragma unroll
        for (int k = 0; k < 2; ++k) {
            const int f = t + k * 256;
            if (f < 384) {
                const int r = f / 12, c = f % 12;
                const float* src = src_base + (size_t)r * XCOLS + c * 4;
                __builtin_amdgcn_global_load_lds(
                    (const __attribute__((address_space(1))) void*)src,
                    (__attribute__((address_space(3))) void*)&xs[f * 4],
                    16, 0, 0);
            }
        }
    }

    // ---- stage params for 16 groups as bf16: 1728 float4 -> cvt_pk -> b64.
    // group pgl at elem pgl*444; float4 f covers elems rem*4..rem*4+3.
    {
        const float4* src = reinterpret_cast<const float4*>(P + (size_t)g0 * (NV * OUT_DIM));
        #pragma unroll
        for (int k = 0; k < 7; ++k) {
            const int f = t + k * 256;
            if (f < 1728) {
                const float4 v = src[f];
                const int pgl = f / 108;          // 108 float4 per group
                const int rem = f - pgl * 108;
                u32x2 w;
                w.x = cvt_pk_bf16(v.x, v.y);
                w.y = cvt_pk_bf16(v.z, v.w);
                *reinterpret_cast<u32x2*>(&ps[pgl * PSTRIDE + rem * 4]) = w;
            }
        }
    }

    __syncthreads();   // drains global_load_lds (vmcnt) + ds_writes (lgkmcnt)

    const int wv = t >> 6;
    const int l  = t & 63;
    const int gl = l >> 2;    // group-local 0..15
    const int oq = l & 3;     // which float4 of the 16 outputs

    // per-lane bases
    const unsigned short* pbase = ps + gl * PSTRIDE + oq * 4;  // + vb*16 at runtime
    const float* xb = xs + gl * ARITY;
    // within-block out col = gl*16 + oq*4 = 4*l -> wave writes 1KB contiguous
    float* outp = out + (size_t)b0 * OCOLS + (size_t)g0 * OUT_DIM + l * 4;

    #pragma unroll 2
    for (int i = 0; i < 8; ++i) {
        const int b = wv * 8 + i;
        const float x0 = xb[b * (GTILE * ARITY) + 0];
        const float x1 = xb[b * (GTILE * ARITY) + 1];
        const float x2 = xb[b * (GTILE * ARITY) + 2];

        // containing cell per dim; lower/upper hat weights (3rd weight == 0)
        const bool n0 = x0 < 0.0f, n1 = x1 < 0.0f, n2 = x2 < 0.0f;
        const float wl0 = n0 ? -x0       : 1.0f - x0;
        const float wh0 = n0 ? 1.0f + x0 : x0;
        const float wl1 = n1 ? -x1       : 1.0f - x1;
        const float wh1 = n1 ? 1.0f + x1 : x1;
        const float wl2 = n2 ? -x2       : 1.0f - x2;
        const float wh2 = n2 ? 1.0f + x2 : x2;
        const int   vb  = (n0 ? 0 : 1) + 3 * (n1 ? 0 : 1) + 9 * (n2 ? 0 : 1);

        // 8 corner weights
        const float wA = wl0 * wl1, wB = wh0 * wl1, wC = wl0 * wh1, wD = wh0 * wh1;
        const float c000 = wA * wl2, c100 = wB * wl2, c010 = wC * wl2, c110 = wD * wl2;
        const float c001 = wA * wh2, c101 = wB * wh2, c011 = wC * wh2, c111 = wD * wh2;

        // one runtime base + 8 immediate-offset ds_read_b64 (4 bf16 each);
        // vertex dv in u32x2 units: dv*4 (dv*16 elems)
        const u32x2* pp = reinterpret_cast<const u32x2*>(pbase + (size_t)vb * 16);
        const u32x2 r0 = pp[0];        // dv=0  (c000)
        const u32x2 r1 = pp[4];        // dv=1  (c100)
        const u32x2 r2 = pp[12];       // dv=3  (c010)
        const u32x2 r3 = pp[16];       // dv=4  (c110)
        const u32x2 r4 = pp[36];       // dv=9  (c001)
        const u32x2 r5 = pp[40];       // dv=10 (c101)
        const u32x2 r6 = pp[48];       // dv=12 (c011)
        const u32x2 r7 = pp[52];       // dv=13 (c111)

        f32x4 acc;
        {
            f32x4 pv = { bflo(r0.x), bfhi(r0.x), bflo(r0.y), bfhi(r0.y) };
            acc = c000 * pv;
        }
        { f32x4 pv = { bflo(r1.x), bfhi(r1.x), bflo(r1.y), bfhi(r1.y) }; acc += c100 * pv; }
        { f32x4 pv = { bflo(r2.x), bfhi(r2.x), bflo(r2.y), bfhi(r2.y) }; acc += c010 * pv; }
        { f32x4 pv = { bflo(r3.x), bfhi(r3.x), bflo(r3.y), bfhi(r3.y) }; acc += c110 * pv; }
        { f32x4 pv = { bflo(r4.x), bfhi(r4.x), bflo(r4.y), bfhi(r4.y) }; acc += c001 * pv; }
        { f32x4 pv = { bflo(r5.x), bfhi(r5.x), bflo(r5.y), bfhi(r5.y) }; acc += c101 * pv; }
        { f32x4 pv = { bflo(r6.x), bfhi(r6.x), bflo(r6.y), bfhi(r6.y) }; acc += c011 * pv; }
        { f32x4 pv = { bflo(r7.x), bfhi(r7.x), bflo(r7.y), bfhi(r7.y) }; acc += c111 * pv; }

        __builtin_nontemporal_store(acc,
            reinterpret_cast<f32x4*>(outp + (size_t)b * OCOLS));
    }
}

extern "C" void kernel_launch(void* const* d_in, const int* in_sizes, int n_in,
                              void* d_out, int out_size, void* d_ws, size_t ws_size,
                              hipStream_t stream) {
    const float* X = (const float*)d_in[0];   // [8192, 1536] f32
    const float* P = (const float*)d_in[1];   // [512, 27, 16] f32
    float* out = (float*)d_out;               // [8192, 8192] f32

    dim3 grid(BATCH / BTILE, GROUPS / GTILE); // 256 x 32 = 8192 blocks
    dim3 block(256);
    lattice_interp_kernel<<<grid, block, 0, stream>>>(X, P, out);
}

// Round 10
// 62.492 us; speedup vs baseline: 1.8413x; 1.1639x over previous
//
#include <hip/hip_runtime.h>

// Problem constants (fixed by the reference)
#define BATCH   8192
#define GROUPS  512
#define ARITY   3
#define OUT_DIM 16
#define NV      27          // 3^3 vertices
#define XCOLS   (GROUPS*ARITY)      // 1536
#define OCOLS   (GROUPS*OUT_DIM)    // 8192

// R10 = R9 with ONE change: grid axes swapped so the fast-varying block
// index walks GROUP chunks, not batch chunks. Concurrently-resident blocks
// then cover all 32 g-chunks x 64 b-chunks = 2048 COMPLETE output rows ->
// each 32KB DRAM row is fully written within a tight window (row-buffer
// hits) instead of receiving 1KB now and 31KB across the whole kernel.
// Hypothesis: nt-write efficiency 4.4 -> ~6 TB/s.
#define BTILE 32
#define GTILE 16
#define PSTRIDE 444     // bf16 elems per group (432 + 12 pad)

typedef float    f32x4 __attribute__((ext_vector_type(4)));
typedef unsigned u32x2 __attribute__((ext_vector_type(2)));

__device__ __forceinline__ unsigned cvt_pk_bf16(float lo, float hi) {
    unsigned r;
    asm("v_cvt_pk_bf16_f32 %0, %1, %2" : "=v"(r) : "v"(lo), "v"(hi));
    return r;
}
__device__ __forceinline__ float bflo(unsigned u) {
    union { unsigned u; float f; } c; c.u = u << 16; return c.f;
}
__device__ __forceinline__ float bfhi(unsigned u) {
    union { unsigned u; float f; } c; c.u = u & 0xffff0000u; return c.f;
}

__global__ __launch_bounds__(256, 8) void lattice_interp_kernel(
    const float* __restrict__ X,
    const float* __restrict__ P,
    float* __restrict__ out)
{
    __shared__ float xs[BTILE * GTILE * ARITY];        // 1536 f32 = 6144 B
    __shared__ unsigned short ps[GTILE * PSTRIDE];     // 7104 bf16 = 14208 B

    const int t  = threadIdx.x;
    const int b0 = blockIdx.y * BTILE;   // batch chunk: SLOW grid dim
    const int g0 = blockIdx.x * GTILE;   // group chunk: FAST grid dim

    // ---- stage X rows [b0,b0+32) cols [g0*3, g0*3+48): 384 float4, linear.
    {
        const float* src_base = X + (size_t)b0 * XCOLS + g0 * ARITY;
        #pragma unroll
        for (int k = 0; k < 2; ++k) {
            const int f = t + k * 256;
            if (f < 384) {
                const int r = f / 12, c = f % 12;
                const float* src = src_base + (size_t)r * XCOLS + c * 4;
                __builtin_amdgcn_global_load_lds(
                    (const __attribute__((address_space(1))) void*)src,
                    (__attribute__((address_space(3))) void*)&xs[f * 4],
                    16, 0, 0);
            }
        }
    }

    // ---- stage params for 16 groups as bf16: 1728 float4 -> cvt_pk -> b64.
    // group pgl at elem pgl*444; float4 f covers elems rem*4..rem*4+3.
    {
        const float4* src = reinterpret_cast<const float4*>(P + (size_t)g0 * (NV * OUT_DIM));
        #pragma unroll
        for (int k = 0; k < 7; ++k) {
            const int f = t + k * 256;
            if (f < 1728) {
                const float4 v = src[f];
                const int pgl = f / 108;          // 108 float4 per group
                const int rem = f - pgl * 108;
                u32x2 w;
                w.x = cvt_pk_bf16(v.x, v.y);
                w.y = cvt_pk_bf16(v.z, v.w);
                *reinterpret_cast<u32x2*>(&ps[pgl * PSTRIDE + rem * 4]) = w;
            }
        }
    }

    __syncthreads();   // drains global_load_lds (vmcnt) + ds_writes (lgkmcnt)

    const int wv = t >> 6;
    const int l  = t & 63;
    const int gl = l >> 2;    // group-local 0..15
    const int oq = l & 3;     // which float4 of the 16 outputs

    // per-lane bases
    const unsigned short* pbase = ps + gl * PSTRIDE + oq * 4;  // + vb*16 at runtime
    const float* xb = xs + gl * ARITY;
    // within-block out col = gl*16 + oq*4 = 4*l -> wave writes 1KB contiguous
    float* outp = out + (size_t)b0 * OCOLS + (size_t)g0 * OUT_DIM + l * 4;

    #pragma unroll 2
    for (int i = 0; i < 8; ++i) {
        const int b = wv * 8 + i;
        const float x0 = xb[b * (GTILE * ARITY) + 0];
        const float x1 = xb[b * (GTILE * ARITY) + 1];
        const float x2 = xb[b * (GTILE * ARITY) + 2];

        // containing cell per dim; lower/upper hat weights (3rd weight == 0)
        const bool n0 = x0 < 0.0f, n1 = x1 < 0.0f, n2 = x2 < 0.0f;
        const float wl0 = n0 ? -x0       : 1.0f - x0;
        const float wh0 = n0 ? 1.0f + x0 : x0;
        const float wl1 = n1 ? -x1       : 1.0f - x1;
        const float wh1 = n1 ? 1.0f + x1 : x1;
        const float wl2 = n2 ? -x2       : 1.0f - x2;
        const float wh2 = n2 ? 1.0f + x2 : x2;
        const int   vb  = (n0 ? 0 : 1) + 3 * (n1 ? 0 : 1) + 9 * (n2 ? 0 : 1);

        // 8 corner weights
        const float wA = wl0 * wl1, wB = wh0 * wl1, wC = wl0 * wh1, wD = wh0 * wh1;
        const float c000 = wA * wl2, c100 = wB * wl2, c010 = wC * wl2, c110 = wD * wl2;
        const float c001 = wA * wh2, c101 = wB * wh2, c011 = wC * wh2, c111 = wD * wh2;

        // one runtime base + 8 immediate-offset ds_read_b64 (4 bf16 each);
        // vertex dv in u32x2 units: dv*4 (dv*16 elems)
        const u32x2* pp = reinterpret_cast<const u32x2*>(pbase + (size_t)vb * 16);
        const u32x2 r0 = pp[0];        // dv=0  (c000)
        const u32x2 r1 = pp[4];        // dv=1  (c100)
        const u32x2 r2 = pp[12];       // dv=3  (c010)
        const u32x2 r3 = pp[16];       // dv=4  (c110)
        const u32x2 r4 = pp[36];       // dv=9  (c001)
        const u32x2 r5 = pp[40];       // dv=10 (c101)
        const u32x2 r6 = pp[48];       // dv=12 (c011)
        const u32x2 r7 = pp[52];       // dv=13 (c111)

        f32x4 acc;
        {
            f32x4 pv = { bflo(r0.x), bfhi(r0.x), bflo(r0.y), bfhi(r0.y) };
            acc = c000 * pv;
        }
        { f32x4 pv = { bflo(r1.x), bfhi(r1.x), bflo(r1.y), bfhi(r1.y) }; acc += c100 * pv; }
        { f32x4 pv = { bflo(r2.x), bfhi(r2.x), bflo(r2.y), bfhi(r2.y) }; acc += c010 * pv; }
        { f32x4 pv = { bflo(r3.x), bfhi(r3.x), bflo(r3.y), bfhi(r3.y) }; acc += c110 * pv; }
        { f32x4 pv = { bflo(r4.x), bfhi(r4.x), bflo(r4.y), bfhi(r4.y) }; acc += c001 * pv; }
        { f32x4 pv = { bflo(r5.x), bfhi(r5.x), bflo(r5.y), bfhi(r5.y) }; acc += c101 * pv; }
        { f32x4 pv = { bflo(r6.x), bfhi(r6.x), bflo(r6.y), bfhi(r6.y) }; acc += c011 * pv; }
        { f32x4 pv = { bflo(r7.x), bfhi(r7.x), bflo(r7.y), bfhi(r7.y) }; acc += c111 * pv; }

        __builtin_nontemporal_store(acc,
            reinterpret_cast<f32x4*>(outp + (size_t)b * OCOLS));
    }
}

extern "C" void kernel_launch(void* const* d_in, const int* in_sizes, int n_in,
                              void* d_out, int out_size, void* d_ws, size_t ws_size,
                              hipStream_t stream) {
    const float* X = (const float*)d_in[0];   // [8192, 1536] f32
    const float* P = (const float*)d_in[1];   // [512, 27, 16] f32
    float* out = (float*)d_out;               // [8192, 8192] f32

    dim3 grid(GROUPS / GTILE, BATCH / BTILE); // 32 x 256 (g fast, b slow)
    dim3 block(256);
    lattice_interp_kernel<<<grid, block, 0, stream>>>(X, P, out);
}

// Round 11
// 60.030 us; speedup vs baseline: 1.9168x; 1.0410x over previous
//
#include <hip/hip_runtime.h>

// Problem constants (fixed by the reference)
#define BATCH   8192
#define GROUPS  512
#define ARITY   3
#define OUT_DIM 16
#define NV      27          // 3^3 vertices
#define XCOLS   (GROUPS*ARITY)      // 1536
#define OCOLS   (GROUPS*OUT_DIM)    // 8192

// R11 = R10 + block persistence: grid (32 g-fast x 64) = 2048 blocks =
// exactly 8/CU = ONE residency round. Each block stages params ONCE, then
// loops NCHUNK=4 consecutive b-chunks (stage X -> barrier -> compute ->
// barrier). Param staging traffic /4 (226->56MB L2), prologue amortized,
// zero round quantization. Compute body identical to R10.
#define BTILE 32
#define NCHUNK 4
#define GTILE 16
#define PSTRIDE 444     // bf16 elems per group (432 + 12 pad)

typedef float    f32x4 __attribute__((ext_vector_type(4)));
typedef unsigned u32x2 __attribute__((ext_vector_type(2)));

__device__ __forceinline__ unsigned cvt_pk_bf16(float lo, float hi) {
    unsigned r;
    asm("v_cvt_pk_bf16_f32 %0, %1, %2" : "=v"(r) : "v"(lo), "v"(hi));
    return r;
}
__device__ __forceinline__ float bflo(unsigned u) {
    union { unsigned u; float f; } c; c.u = u << 16; return c.f;
}
__device__ __forceinline__ float bfhi(unsigned u) {
    union { unsigned u; float f; } c; c.u = u & 0xffff0000u; return c.f;
}

__global__ __launch_bounds__(256, 8) void lattice_interp_kernel(
    const float* __restrict__ X,
    const float* __restrict__ P,
    float* __restrict__ out)
{
    __shared__ float xs[BTILE * GTILE * ARITY];        // 1536 f32 = 6144 B
    __shared__ unsigned short ps[GTILE * PSTRIDE];     // 7104 bf16 = 14208 B

    const int t  = threadIdx.x;
    const int g0 = blockIdx.x * GTILE;              // group chunk: FAST dim
    const int bbase = blockIdx.y * (BTILE * NCHUNK); // 128-batch span: SLOW

    // ---- stage params for 16 groups as bf16 (ONCE per block):
    // 1728 float4 -> cvt_pk -> ds_write_b64. group pgl at elem pgl*444.
    {
        const float4* src = reinterpret_cast<const float4*>(P + (size_t)g0 * (NV * OUT_DIM));
        #pragma unroll
        for (int k = 0; k < 7; ++k) {
            const int f = t + k * 256;
            if (f < 1728) {
                const float4 v = src[f];
                const int pgl = f / 108;          // 108 float4 per group
                const int rem = f - pgl * 108;
                u32x2 w;
                w.x = cvt_pk_bf16(v.x, v.y);
                w.y = cvt_pk_bf16(v.z, v.w);
                *reinterpret_cast<u32x2*>(&ps[pgl * PSTRIDE + rem * 4]) = w;
            }
        }
    }

    // ---- stage X chunk 0: rows [bbase, bbase+32) cols [g0*3, g0*3+48).
    {
        const float* src_base = X + (size_t)bbase * XCOLS + g0 * ARITY;
        #pragma unroll
        for (int k = 0; k < 2; ++k) {
            const int f = t + k * 256;
            if (f < 384) {
                const int r = f / 12, c = f % 12;
                __builtin_amdgcn_global_load_lds(
                    (const __attribute__((address_space(1))) void*)(src_base + (size_t)r * XCOLS + c * 4),
                    (__attribute__((address_space(3))) void*)&xs[f * 4],
                    16, 0, 0);
            }
        }
    }

    __syncthreads();   // drains global_load_lds (vmcnt) + ds_writes (lgkmcnt)

    const int wv = t >> 6;
    const int l  = t & 63;
    const int gl = l >> 2;    // group-local 0..15
    const int oq = l & 3;     // which float4 of the 16 outputs

    const unsigned short* pbase = ps + gl * PSTRIDE + oq * 4;  // + vb*16 at runtime
    const float* xb = xs + gl * ARITY;

    #pragma unroll 1
    for (int j = 0; j < NCHUNK; ++j) {
        const int b0 = bbase + j * BTILE;
        // within-block out col = gl*16 + oq*4 = 4*l -> wave writes 1KB contiguous
        float* outp = out + (size_t)b0 * OCOLS + (size_t)g0 * OUT_DIM + l * 4;

        #pragma unroll 2
        for (int i = 0; i < 8; ++i) {
            const int b = wv * 8 + i;
            const float x0 = xb[b * (GTILE * ARITY) + 0];
            const float x1 = xb[b * (GTILE * ARITY) + 1];
            const float x2 = xb[b * (GTILE * ARITY) + 2];

            // containing cell per dim; lower/upper hat weights (3rd == 0)
            const bool n0 = x0 < 0.0f, n1 = x1 < 0.0f, n2 = x2 < 0.0f;
            const float wl0 = n0 ? -x0       : 1.0f - x0;
            const float wh0 = n0 ? 1.0f + x0 : x0;
            const float wl1 = n1 ? -x1       : 1.0f - x1;
            const float wh1 = n1 ? 1.0f + x1 : x1;
            const float wl2 = n2 ? -x2       : 1.0f - x2;
            const float wh2 = n2 ? 1.0f + x2 : x2;
            const int   vb  = (n0 ? 0 : 1) + 3 * (n1 ? 0 : 1) + 9 * (n2 ? 0 : 1);

            // 8 corner weights
            const float wA = wl0 * wl1, wB = wh0 * wl1, wC = wl0 * wh1, wD = wh0 * wh1;
            const float c000 = wA * wl2, c100 = wB * wl2, c010 = wC * wl2, c110 = wD * wl2;
            const float c001 = wA * wh2, c101 = wB * wh2, c011 = wC * wh2, c111 = wD * wh2;

            // one runtime base + 8 immediate-offset ds_read_b64 (4 bf16 each)
            const u32x2* pp = reinterpret_cast<const u32x2*>(pbase + (size_t)vb * 16);
            const u32x2 r0 = pp[0];        // dv=0  (c000)
            const u32x2 r1 = pp[4];        // dv=1  (c100)
            const u32x2 r2 = pp[12];       // dv=3  (c010)
            const u32x2 r3 = pp[16];       // dv=4  (c110)
            const u32x2 r4 = pp[36];       // dv=9  (c001)
            const u32x2 r5 = pp[40];       // dv=10 (c101)
            const u32x2 r6 = pp[48];       // dv=12 (c011)
            const u32x2 r7 = pp[52];       // dv=13 (c111)

            f32x4 acc;
            { f32x4 pv = { bflo(r0.x), bfhi(r0.x), bflo(r0.y), bfhi(r0.y) }; acc  = c000 * pv; }
            { f32x4 pv = { bflo(r1.x), bfhi(r1.x), bflo(r1.y), bfhi(r1.y) }; acc += c100 * pv; }
            { f32x4 pv = { bflo(r2.x), bfhi(r2.x), bflo(r2.y), bfhi(r2.y) }; acc += c010 * pv; }
            { f32x4 pv = { bflo(r3.x), bfhi(r3.x), bflo(r3.y), bfhi(r3.y) }; acc += c110 * pv; }
            { f32x4 pv = { bflo(r4.x), bfhi(r4.x), bflo(r4.y), bfhi(r4.y) }; acc += c001 * pv; }
            { f32x4 pv = { bflo(r5.x), bfhi(r5.x), bflo(r5.y), bfhi(r5.y) }; acc += c101 * pv; }
            { f32x4 pv = { bflo(r6.x), bfhi(r6.x), bflo(r6.y), bfhi(r6.y) }; acc += c011 * pv; }
            { f32x4 pv = { bflo(r7.x), bfhi(r7.x), bflo(r7.y), bfhi(r7.y) }; acc += c111 * pv; }

            __builtin_nontemporal_store(acc,
                reinterpret_cast<f32x4*>(outp + (size_t)b * OCOLS));
        }

        __syncthreads();   // all waves done reading xs before restage

        if (j + 1 < NCHUNK) {
            const float* src_base = X + (size_t)(bbase + (j + 1) * BTILE) * XCOLS + g0 * ARITY;
            #pragma unroll
            for (int k = 0; k < 2; ++k) {
                const int f = t + k * 256;
                if (f < 384) {
                    const int r = f / 12, c = f % 12;
                    __builtin_amdgcn_global_load_lds(
                        (const __attribute__((address_space(1))) void*)(src_base + (size_t)r * XCOLS + c * 4),
                        (__attribute__((address_space(3))) void*)&xs[f * 4],
                        16, 0, 0);
                }
            }
            __syncthreads();   // staging complete before compute reads
        }
    }
}

extern "C" void kernel_launch(void* const* d_in, const int* in_sizes, int n_in,
                              void* d_out, int out_size, void* d_ws, size_t ws_size,
                              hipStream_t stream) {
    const float* X = (const float*)d_in[0];   // [8192, 1536] f32
    const float* P = (const float*)d_in[1];   // [512, 27, 16] f32
    float* out = (float*)d_out;               // [8192, 8192] f32

    dim3 grid(GROUPS / GTILE, BATCH / (BTILE * NCHUNK)); // 32 x 64 = 2048
    dim3 block(256);
    lattice_interp_kernel<<<grid, block, 0, stream>>>(X, P, out);
}